// Round 3
// baseline (301.911 us; speedup 1.0000x reference)
//
#include <hip/hip_runtime.h>
#include <math.h>
#include <stdint.h>

#define NUM_BINS 20
#define NPAIR    (NUM_BINS / 2)    // bins packed in adjacent pairs (2j, 2j+1)
#define NACC     (3 * NUM_BINS)    // 60 scalar accumulators total
#define BLOCK    256
#define NBLK     1024              // 4 blocks/CU; reg cap is ~4 waves/SIMD anyway
#define TILEF    (BLOCK * 4)       // floats per tile per array (256 float4 = 4 KB)

typedef float v2f __attribute__((ext_vector_type(2)));
typedef __attribute__((address_space(3))) uint32_t       lds_u32_t;
typedef __attribute__((address_space(1))) const uint32_t glb_u32_t;

// w_j(p) = exp(-(p - c_j)^2 / T) = exp2(K1*p*p) * exp2(K2*p)^j * exp2(K1*c_j*c_j)
//   K1 = -1/(T*ln2), K2 = 2/(19*T*ln2), T = 0.1, c_j = j/19
__device__ __host__ constexpr float K1f() { return (float)(-1.0 / (0.1 * 0.6931471805599453)); }
__device__ __host__ constexpr float K2f() { return (float)( 2.0 / (1.9 * 0.6931471805599453)); }

// async global->LDS, 16B per lane; LDS dest is wave-uniform base + lane*16
__device__ __forceinline__ void stage16(const float4* gsrc, float* ldst) {
    __builtin_amdgcn_global_load_lds((glb_u32_t*)gsrc, (lds_u32_t*)ldst, 16, 0, 0);
}

__global__ __launch_bounds__(BLOCK, 4) void ace_partial(const float* __restrict__ p,
                                                        const float* __restrict__ t,
                                                        float* __restrict__ partials,
                                                        int n4, int nblk) {
    __shared__ float ldsP[2][TILEF];   // 2 x 4 KB
    __shared__ float ldsT[2][TILEF];   // 2 x 4 KB   (16 KB total)

    const float K1 = K1f();
    const float K2 = K2f();

    v2f aW2[NPAIR], aP2[NPAIR], aT2[NPAIR];
#pragma unroll
    for (int jp = 0; jp < NPAIR; ++jp) {
        aW2[jp] = (v2f){0.f, 0.f};
        aP2[jp] = (v2f){0.f, 0.f};
        aT2[jp] = (v2f){0.f, 0.f};
    }

    const float4* __restrict__ p4 = (const float4*)p;
    const float4* __restrict__ t4 = (const float4*)t;

    const int tid    = threadIdx.x;
    const int wave   = tid >> 6;
    const int stride = gridDim.x * BLOCK;
    int gidx         = blockIdx.x * BLOCK + tid;
    const int niter  = n4 / stride;

    float* const ldsPbase = &ldsP[0][0];
    float* const ldsTbase = &ldsT[0][0];
    const int waveOff = wave * 256;    // 64 lanes * 4 floats

    int cur = 0;
    if (niter > 0) {
        // prologue: stage tile 0 into buffer 0
        stage16(p4 + gidx, ldsPbase + waveOff);
        stage16(t4 + gidx, ldsTbase + waveOff);
        asm volatile("s_waitcnt vmcnt(0)" ::: "memory");
        __syncthreads();
    }

    for (int k = 0; k < niter; ++k) {
        const int gnext = gidx + stride;
        if (k + 1 < niter) {
            const int nb = cur ^ 1;
            stage16(p4 + gnext, ldsPbase + nb * TILEF + waveOff);
            stage16(t4 + gnext, ldsTbase + nb * TILEF + waveOff);
        }

        // own float4s from current buffer (contiguous ds_read_b128, conflict-free)
        const float4 pv = *(const float4*)(ldsPbase + cur * TILEF + tid * 4);
        const float4 tv = *(const float4*)(ldsTbase + cur * TILEF + tid * 4);

        float pe[4] = {pv.x, pv.y, pv.z, pv.w};
        float te[4] = {tv.x, tv.y, tv.z, tv.w};

#pragma unroll
        for (int e = 0; e < 4; ++e) {
            float pp = pe[e];
            float tt = te[e];
            float u  = __builtin_amdgcn_exp2f(K1 * pp * pp);  // exp(-p^2/T)
            float G  = __builtin_amdgcn_exp2f(K2 * pp);       // exp(2p/(19T))
            float GG = G * G;
            v2f g2;  g2.x = u;  g2.y = u * G;                 // (u*G^{2jp}, u*G^{2jp+1})
            v2f GG2 = (v2f){GG, GG};
            v2f pp2 = (v2f){pp, pp};
            v2f tt2 = (v2f){tt, tt};
#pragma unroll
            for (int jp = 0; jp < NPAIR; ++jp) {
                aW2[jp] += g2;                                          // v_pk_add_f32
                aP2[jp]  = __builtin_elementwise_fma(g2, pp2, aP2[jp]); // v_pk_fma_f32
                aT2[jp]  = __builtin_elementwise_fma(g2, tt2, aT2[jp]); // v_pk_fma_f32
                g2      *= GG2;                                         // v_pk_mul_f32
            }
        }

        // barrier: compiler drains vmcnt(0) here -> next tile complete, all waves done reading cur
        __syncthreads();
        cur ^= 1;
        gidx = gnext;
    }

    // tail (n4 % stride != 0 case; zero for the production shape) — direct global path
    for (int i = gidx; i < n4; i += stride) {
        float4 pv = p4[i];
        float4 tv = t4[i];
        float pe[4] = {pv.x, pv.y, pv.z, pv.w};
        float te[4] = {tv.x, tv.y, tv.z, tv.w};
#pragma unroll
        for (int e = 0; e < 4; ++e) {
            float pp = pe[e];
            float tt = te[e];
            float u  = __builtin_amdgcn_exp2f(K1 * pp * pp);
            float G  = __builtin_amdgcn_exp2f(K2 * pp);
            float GG = G * G;
            v2f g2;  g2.x = u;  g2.y = u * G;
            v2f GG2 = (v2f){GG, GG};
            v2f pp2 = (v2f){pp, pp};
            v2f tt2 = (v2f){tt, tt};
#pragma unroll
            for (int jp = 0; jp < NPAIR; ++jp) {
                aW2[jp] += g2;
                aP2[jp]  = __builtin_elementwise_fma(g2, pp2, aP2[jp]);
                aT2[jp]  = __builtin_elementwise_fma(g2, tt2, aT2[jp]);
                g2      *= GG2;
            }
        }
    }

    // Wave(64)-level tree reduction of all 60 scalar accumulators
#pragma unroll
    for (int jp = 0; jp < NPAIR; ++jp) {
#pragma unroll
        for (int off = 32; off > 0; off >>= 1) {
            aW2[jp].x += __shfl_down(aW2[jp].x, off, 64);
            aW2[jp].y += __shfl_down(aW2[jp].y, off, 64);
            aP2[jp].x += __shfl_down(aP2[jp].x, off, 64);
            aP2[jp].y += __shfl_down(aP2[jp].y, off, 64);
            aT2[jp].x += __shfl_down(aT2[jp].x, off, 64);
            aT2[jp].y += __shfl_down(aT2[jp].y, off, 64);
        }
    }

    __shared__ float red[BLOCK / 64][NACC];
    int lane = threadIdx.x & 63;
    if (lane == 0) {
#pragma unroll
        for (int jp = 0; jp < NPAIR; ++jp) {
            red[wave][2 * jp]                    = aW2[jp].x;
            red[wave][2 * jp + 1]                = aW2[jp].y;
            red[wave][NUM_BINS + 2 * jp]         = aP2[jp].x;
            red[wave][NUM_BINS + 2 * jp + 1]     = aP2[jp].y;
            red[wave][2 * NUM_BINS + 2 * jp]     = aT2[jp].x;
            red[wave][2 * NUM_BINS + 2 * jp + 1] = aT2[jp].y;
        }
    }
    __syncthreads();

    // Transposed layout: partials[acc_idx * nblk + blockIdx.x] so the final kernel reads coalesced
    if (threadIdx.x < NACC) {
        float s = 0.f;
#pragma unroll
        for (int w = 0; w < BLOCK / 64; ++w) s += red[w][threadIdx.x];
        partials[threadIdx.x * nblk + blockIdx.x] = s;
    }
}

__global__ __launch_bounds__(1024) void ace_final(const float* __restrict__ partials,
                                                  float* __restrict__ out,
                                                  int nblk) {
    const float K1 = K1f();

    __shared__ float red[NACC][16];
    __shared__ float sums[NACC];
    int tid = threadIdx.x;

    if (tid < NACC * 16) {
        int j = tid >> 4;
        int k = tid & 15;
        float s = 0.f;
        // consecutive k -> consecutive b -> coalesced
        for (int b = k; b < nblk; b += 16) s += partials[j * nblk + b];
        red[j][k] = s;
    }
    __syncthreads();

    if (tid < NACC) {
        float s = 0.f;
#pragma unroll
        for (int k = 0; k < 16; ++k) s += red[tid][k];
        sums[tid] = s;
    }
    __syncthreads();

    if (tid == 0) {
        float acc = 0.f;
        for (int j = 0; j < NUM_BINS; ++j) {
            float c    = (float)j / 19.0f;
            float A    = __builtin_amdgcn_exp2f(K1 * c * c);  // exp(-c^2/T)
            float wsum = A * sums[j];
            float denom = wsum + 1e-8f;
            float e    = (A * sums[NUM_BINS + j]) / denom;
            float o    = (A * sums[2 * NUM_BINS + j]) / denom;
            float contrib = (wsum == 0.0f) ? 0.0f : fabsf(e - o);
            acc += contrib;
        }
        out[0] = acc / (float)NUM_BINS;
    }
}

extern "C" void kernel_launch(void* const* d_in, const int* in_sizes, int n_in,
                              void* d_out, int out_size, void* d_ws, size_t ws_size,
                              hipStream_t stream) {
    const float* preds   = (const float*)d_in[0];
    const float* targets = (const float*)d_in[1];
    float* out           = (float*)d_out;
    float* partials      = (float*)d_ws;

    int n  = in_sizes[0];
    int n4 = n >> 2;   // N = 32*1024*1024, divisible by 4

    int nblk = NBLK;
    size_t need = (size_t)nblk * NACC * sizeof(float);
    if (ws_size < need) {
        nblk = (int)(ws_size / (NACC * sizeof(float)));
        if (nblk < 1) nblk = 1;
    }

    ace_partial<<<nblk, BLOCK, 0, stream>>>(preds, targets, partials, n4, nblk);
    ace_final<<<1, 1024, 0, stream>>>(partials, out, nblk);
}

// Round 4
// 294.669 us; speedup vs baseline: 1.0246x; 1.0246x over previous
//
#include <hip/hip_runtime.h>
#include <math.h>
#include <stdint.h>

#define NUM_BINS 20
#define NPAIR    (NUM_BINS / 2)    // bins packed in adjacent pairs (2j, 2j+1)
#define NACC     (3 * NUM_BINS)    // 60 scalar accumulators total
#define BLOCK    256
#define NBLK     1024              // 4 blocks/CU
#define DEPTH    4                 // wave-private LDS ring slots (3 chunks in flight)
#define CHUNKF   256               // floats per wave per chunk per array (64 lanes x 4)
#define NWAVES   (BLOCK / 64)

typedef float v2f __attribute__((ext_vector_type(2)));
typedef __attribute__((address_space(3))) uint32_t       lds_u32_t;
typedef __attribute__((address_space(1))) const uint32_t glb_u32_t;

// w_j(p) = exp(-(p - c_j)^2 / T) = exp2(K1*p*p) * exp2(K2*p)^j * exp2(K1*c_j*c_j)
//   K1 = -1/(T*ln2), K2 = 2/(19*T*ln2), T = 0.1, c_j = j/19
__device__ __host__ constexpr float K1f() { return (float)(-1.0 / (0.1 * 0.6931471805599453)); }
__device__ __host__ constexpr float K2f() { return (float)( 2.0 / (1.9 * 0.6931471805599453)); }

// async global->LDS, 16B per lane; LDS dest = wave-uniform base + lane*16
__device__ __forceinline__ void stage16(const float4* gsrc, float* ldst) {
    __builtin_amdgcn_global_load_lds((glb_u32_t*)gsrc, (lds_u32_t*)ldst, 16, 0, 0);
}

// counted waits (immediates must be literals)
#define WAIT_VMCNT(n) asm volatile("s_waitcnt vmcnt(" #n ")" ::: "memory")
#define WAIT_LGKM0()  asm volatile("s_waitcnt lgkmcnt(0)" ::: "memory")

__global__ __launch_bounds__(BLOCK, 4) void ace_partial(const float* __restrict__ p,
                                                        const float* __restrict__ t,
                                                        float* __restrict__ partials,
                                                        int n4, int nblk) {
    // wave-private rings: no inter-wave sharing -> no barriers in the main loop
    __shared__ float ldsP[NWAVES][DEPTH][CHUNKF];   // 16 KB
    __shared__ float ldsT[NWAVES][DEPTH][CHUNKF];   // 16 KB

    const float K1 = K1f();
    const float K2 = K2f();

    v2f aW2[NPAIR], aP2[NPAIR], aT2[NPAIR];
#pragma unroll
    for (int jp = 0; jp < NPAIR; ++jp) {
        aW2[jp] = (v2f){0.f, 0.f};
        aP2[jp] = (v2f){0.f, 0.f};
        aT2[jp] = (v2f){0.f, 0.f};
    }

    const float4* __restrict__ p4 = (const float4*)p;
    const float4* __restrict__ t4 = (const float4*)t;

    const int tid    = threadIdx.x;
    const int wave   = tid >> 6;
    const int lane   = tid & 63;
    const int stride = gridDim.x * BLOCK;
    const int base   = blockIdx.x * BLOCK + tid;
    const int niter  = n4 / stride;     // full chunks (uniform across the wave)

    // prologue: stage chunks 0..DEPTH-2
    const int npre = (niter < DEPTH - 1) ? niter : (DEPTH - 1);
    for (int k = 0; k < npre; ++k) {
        stage16(p4 + base + k * stride, &ldsP[wave][k][0]);
        stage16(t4 + base + k * stride, &ldsT[wave][k][0]);
    }

    for (int k = 0; k < niter; ++k) {
        // wait until chunk k's two loads have landed; keep the rest in flight
        const int rem = niter - 1 - k;
        if (rem >= 2)      { WAIT_VMCNT(4); }   // chunks k+1,k+2 stay outstanding
        else if (rem == 1) { WAIT_VMCNT(2); }
        else               { WAIT_VMCNT(0); }

        const int slot = k & (DEPTH - 1);
        const float4 pv = *(const float4*)&ldsP[wave][slot][lane * 4];
        const float4 tv = *(const float4*)&ldsT[wave][slot][lane * 4];
        WAIT_LGKM0();   // ds_reads landed in VGPRs -> safe to overwrite ring slots below

        // issue chunk k+3 into slot (k+3)%4 (= slot read & drained in iteration k-1)
        if (k + DEPTH - 1 < niter) {
            const int kn = k + DEPTH - 1;
            stage16(p4 + base + kn * stride, &ldsP[wave][kn & (DEPTH - 1)][0]);
            stage16(t4 + base + kn * stride, &ldsT[wave][kn & (DEPTH - 1)][0]);
        }

        float pe[4] = {pv.x, pv.y, pv.z, pv.w};
        float te[4] = {tv.x, tv.y, tv.z, tv.w};

#pragma unroll
        for (int e = 0; e < 4; ++e) {
            float pp = pe[e];
            float tt = te[e];
            float u  = __builtin_amdgcn_exp2f(K1 * pp * pp);  // exp(-p^2/T)
            float G  = __builtin_amdgcn_exp2f(K2 * pp);       // exp(2p/(19T))
            float GG = G * G;
            v2f g2;  g2.x = u;  g2.y = u * G;                 // (u*G^{2jp}, u*G^{2jp+1})
            v2f GG2 = (v2f){GG, GG};
            v2f pp2 = (v2f){pp, pp};
            v2f tt2 = (v2f){tt, tt};
#pragma unroll
            for (int jp = 0; jp < NPAIR; ++jp) {
                aW2[jp] += g2;                                          // v_pk_add_f32
                aP2[jp]  = __builtin_elementwise_fma(g2, pp2, aP2[jp]); // v_pk_fma_f32
                aT2[jp]  = __builtin_elementwise_fma(g2, tt2, aT2[jp]); // v_pk_fma_f32
                g2      *= GG2;                                         // v_pk_mul_f32
            }
        }
    }

    // tail (n4 % stride != 0; zero for the production shape) — direct global path
    for (int i = base + niter * stride; i < n4; i += stride) {
        float4 pv = p4[i];
        float4 tv = t4[i];
        float pe[4] = {pv.x, pv.y, pv.z, pv.w};
        float te[4] = {tv.x, tv.y, tv.z, tv.w};
#pragma unroll
        for (int e = 0; e < 4; ++e) {
            float pp = pe[e];
            float tt = te[e];
            float u  = __builtin_amdgcn_exp2f(K1 * pp * pp);
            float G  = __builtin_amdgcn_exp2f(K2 * pp);
            float GG = G * G;
            v2f g2;  g2.x = u;  g2.y = u * G;
            v2f GG2 = (v2f){GG, GG};
            v2f pp2 = (v2f){pp, pp};
            v2f tt2 = (v2f){tt, tt};
#pragma unroll
            for (int jp = 0; jp < NPAIR; ++jp) {
                aW2[jp] += g2;
                aP2[jp]  = __builtin_elementwise_fma(g2, pp2, aP2[jp]);
                aT2[jp]  = __builtin_elementwise_fma(g2, tt2, aT2[jp]);
                g2      *= GG2;
            }
        }
    }

    // Wave(64)-level tree reduction of all 60 scalar accumulators
#pragma unroll
    for (int jp = 0; jp < NPAIR; ++jp) {
#pragma unroll
        for (int off = 32; off > 0; off >>= 1) {
            aW2[jp].x += __shfl_down(aW2[jp].x, off, 64);
            aW2[jp].y += __shfl_down(aW2[jp].y, off, 64);
            aP2[jp].x += __shfl_down(aP2[jp].x, off, 64);
            aP2[jp].y += __shfl_down(aP2[jp].y, off, 64);
            aT2[jp].x += __shfl_down(aT2[jp].x, off, 64);
            aT2[jp].y += __shfl_down(aT2[jp].y, off, 64);
        }
    }

    __shared__ float red[NWAVES][NACC];
    if (lane == 0) {
#pragma unroll
        for (int jp = 0; jp < NPAIR; ++jp) {
            red[wave][2 * jp]                    = aW2[jp].x;
            red[wave][2 * jp + 1]                = aW2[jp].y;
            red[wave][NUM_BINS + 2 * jp]         = aP2[jp].x;
            red[wave][NUM_BINS + 2 * jp + 1]     = aP2[jp].y;
            red[wave][2 * NUM_BINS + 2 * jp]     = aT2[jp].x;
            red[wave][2 * NUM_BINS + 2 * jp + 1] = aT2[jp].y;
        }
    }
    __syncthreads();

    // Transposed layout: partials[acc_idx * nblk + blockIdx.x] -> coalesced final reads
    if (threadIdx.x < NACC) {
        float s = 0.f;
#pragma unroll
        for (int w = 0; w < NWAVES; ++w) s += red[w][threadIdx.x];
        partials[threadIdx.x * nblk + blockIdx.x] = s;
    }
}

__global__ __launch_bounds__(1024) void ace_final(const float* __restrict__ partials,
                                                  float* __restrict__ out,
                                                  int nblk) {
    const float K1 = K1f();

    __shared__ float red[NACC][16];
    __shared__ float sums[NACC];
    int tid = threadIdx.x;

    if (tid < NACC * 16) {
        int j = tid >> 4;
        int k = tid & 15;
        const float4* row4 = (const float4*)(partials + (size_t)j * nblk);
        int n4b = nblk >> 2;
        float s = 0.f;
        // consecutive k -> consecutive float4 -> coalesced, 4x fewer load instrs
        for (int b = k; b < n4b; b += 16) {
            float4 v = row4[b];
            s += (v.x + v.y) + (v.z + v.w);
        }
        // remainder if nblk not a multiple of 4 (not hit in production)
        for (int b = (n4b << 2) + k; b < nblk; b += 16) s += partials[(size_t)j * nblk + b];
        red[j][k] = s;
    }
    __syncthreads();

    if (tid < NACC) {
        float s = 0.f;
#pragma unroll
        for (int k = 0; k < 16; ++k) s += red[tid][k];
        sums[tid] = s;
    }
    __syncthreads();

    if (tid == 0) {
        float acc = 0.f;
        for (int j = 0; j < NUM_BINS; ++j) {
            float c    = (float)j / 19.0f;
            float A    = __builtin_amdgcn_exp2f(K1 * c * c);  // exp(-c^2/T)
            float wsum = A * sums[j];
            float denom = wsum + 1e-8f;
            float e    = (A * sums[NUM_BINS + j]) / denom;
            float o    = (A * sums[2 * NUM_BINS + j]) / denom;
            float contrib = (wsum == 0.0f) ? 0.0f : fabsf(e - o);
            acc += contrib;
        }
        out[0] = acc / (float)NUM_BINS;
    }
}

extern "C" void kernel_launch(void* const* d_in, const int* in_sizes, int n_in,
                              void* d_out, int out_size, void* d_ws, size_t ws_size,
                              hipStream_t stream) {
    const float* preds   = (const float*)d_in[0];
    const float* targets = (const float*)d_in[1];
    float* out           = (float*)d_out;
    float* partials      = (float*)d_ws;

    int n  = in_sizes[0];
    int n4 = n >> 2;   // N = 32*1024*1024, divisible by 4

    int nblk = NBLK;
    size_t need = (size_t)nblk * NACC * sizeof(float);
    if (ws_size < need) {
        nblk = (int)(ws_size / (NACC * sizeof(float)));
        if (nblk < 1) nblk = 1;
    }

    ace_partial<<<nblk, BLOCK, 0, stream>>>(preds, targets, partials, n4, nblk);
    ace_final<<<1, 1024, 0, stream>>>(partials, out, nblk);
}